// Round 6
// baseline (263.224 us; speedup 1.0000x reference)
//
#include <hip/hip_runtime.h>
#include <hip/hip_bf16.h>

// DifferentiableXGB: logits = epilogue(x @ W1^T + b1)
//   split[b,n] = sum_d x[b,d]*W1[n,d] + b1[n]          (n = t*4+k, N=400)
//   S[b,t] = sum_k split[b,t,k]
//   logits[b,j] = sum_t fw[t]*S[b,t]*sum_k sigmoid(split[b,t,k])*fc_w[j,k] + fc_b[j]
//
// V6 = V5 with __launch_bounds__(640, 1).
// R5 post-mortem: (640,2) forced a ~102-VGPR cap (5 waves/SIMD) -> 97 MB of
// scratch spill traffic per dispatch (WRITE_SIZE counter) inside the MFMA
// loop; LDS (137 KB) limits us to 1 block/CU anyway. (640,1) raises the cap
// to ~170 VGPRs (3/3/2/2 waves/SIMD launchability), fitting the ~155-reg
// live set without spills.
//   - BM=128 x BN=400, BK=64, 640 threads (2 mh x 5 nf waves), 256 blocks.
//   - LDS double-buffer, ONE barrier per chunk; c+1 staging overlaps
//     compute(c).
//   - XOR-rotate swizzle phys_sub=(sub+row)&7 -> 0 bank conflicts (R5).
//   - A staged fused from fp32 x (read once from HBM, cvt in regs).
//   - B (W1 bf16 in ws) via global_load_lds dwordx4.

typedef __bf16 bf16x8 __attribute__((ext_vector_type(8)));
typedef float f32x4 __attribute__((ext_vector_type(4)));

#define B_ROWS 32768
#define D_DIM  1024
#define N_COLS 400
#define BM     128
#define BK     64
#define NCHUNK 16          // 1024 / 64
#define THREADS 640        // 10 waves: mh = wave/5 (2), nf = wave%5 (5)
#define NTPW 5             // n-tiles (16 wide) per wave
#define MT   4             // m-tiles (16 tall) per wave (64 rows per mh)

__device__ __forceinline__ unsigned short f2bf(float f) {
    unsigned int u = __float_as_uint(f);
    u += 0x7FFFu + ((u >> 16) & 1u);   // RTNE
    return (unsigned short)(u >> 16);
}
__device__ __forceinline__ unsigned int pk2(float a, float b) {
    return (unsigned int)f2bf(a) | ((unsigned int)f2bf(b) << 16);
}
__device__ __forceinline__ uint4 cvt8u(float4 a, float4 b) {
    uint4 u;
    u.x = pk2(a.x, a.y); u.y = pk2(a.z, a.w);
    u.z = pk2(b.x, b.y); u.w = pk2(b.z, b.w);
    return u;
}
__device__ __forceinline__ bf16x8 cvt8(float4 a, float4 b) {
    return __builtin_bit_cast(bf16x8, cvt8u(a, b));
}

// tiny: W1 fp32 -> bf16 (1.6 MB)
__global__ void cvt_f32_bf16_kernel(const float* __restrict__ in,
                                    unsigned short* __restrict__ out) {
    size_t i = ((size_t)blockIdx.x * 256 + threadIdx.x) * 8;
    float4 v0 = *reinterpret_cast<const float4*>(in + i);
    float4 v1 = *reinterpret_cast<const float4*>(in + i + 4);
    *reinterpret_cast<uint4*>(out + i) = cvt8u(v0, v1);
}

// async 16B/lane global->LDS; lds dest = wave-uniform base + lane*16 (HW)
__device__ __forceinline__ void gl_lds16(const unsigned short* g,
                                         unsigned short* l) {
    __builtin_amdgcn_global_load_lds(
        (const __attribute__((address_space(1))) unsigned int*)g,
        (__attribute__((address_space(3))) unsigned int*)l,
        16, 0, 0);
}

// MODE 0: A fp32 (fused cvt), B bf16 (ws). MODE 2: both fp32, plain loop.
template <int MODE>
__global__ __launch_bounds__(THREADS, 1) void xgb_v6(
    const float* __restrict__ x,
    const void*  __restrict__ b_any,
    const float* __restrict__ b1,
    const float* __restrict__ fw,
    const float* __restrict__ fcw,      // [2,4]
    const float* __restrict__ fcb,      // [2]
    float* __restrict__ out)            // [B,2]
{
    // double-buffered tiles; rows of 64 shorts, sub-chunk = 8 shorts (16 B),
    // swizzle: phys_sub = (sub + row) & 7
    __shared__ __align__(16) unsigned short Abuf[2][BM * BK];       // 32 KB
    __shared__ __align__(16) unsigned short Bbuf[2][N_COLS * BK];   // 100 KB
    __shared__ float Pbuf[BM * NTPW * 2];                           // 5 KB

    const int tid  = threadIdx.x;
    const int wave = tid >> 6;
    const int lane = tid & 63;
    const int quad = lane >> 4;
    const int l15  = lane & 15;
    const int mh   = wave / 5;          // 0..1  (m half: 64 rows)
    const int nf   = wave % 5;          // 0..4  (n fifth: 5 tiles)
    const int row0 = blockIdx.x * BM;

    f32x4 acc[MT][NTPW] = {};

    if (MODE == 0) {
        const unsigned short* w1b = (const unsigned short*)b_any;

        // ---- B staging: 50 dma instrs, 5 per wave. stage s covers rows
        // 8s..8s+7. lane i -> row 8s+(i>>3); it must fetch the logical sub
        // that belongs at phys slot i&7:  sub = ((i&7) - row) & 7.
        const unsigned short* bsrc[5];
        int bdst[5];
        #pragma unroll
        for (int t = 0; t < 5; ++t) {
            const int s  = wave + 10 * t;          // 0..49
            const int rr = lane >> 3;              // row within stage group
            const int c  = ((lane & 7) - rr) & 7;  // logical sub for slot
            bsrc[t] = w1b + (size_t)(s * 8 + rr) * D_DIM + c * 8;
            bdst[t] = s * 512;                     // shorts
        }

        // ---- A staging: 1024 sub-chunks (128 rows x 8 subs), <=2/thread.
        int a_r[2], a_c[2], a_n = 0;
        #pragma unroll
        for (int u = 0; u < 2; ++u) {
            const int i = tid + u * THREADS;
            if (i < BM * 8) { a_r[a_n] = i >> 3; a_c[a_n] = i & 7; ++a_n; }
        }
        float4 areg[2][2];

        auto loadA = [&](int kc) {
            for (int u = 0; u < a_n; ++u) {
                const float* src = x + (size_t)(row0 + a_r[u]) * D_DIM
                                     + kc + a_c[u] * 8;
                areg[u][0] = *reinterpret_cast<const float4*>(src);
                areg[u][1] = *reinterpret_cast<const float4*>(src + 4);
            }
        };
        auto writeA = [&](unsigned short* Ab) {
            for (int u = 0; u < a_n; ++u) {
                const int p = (a_c[u] + a_r[u]) & 7;     // swizzled slot
                *reinterpret_cast<uint4*>(Ab + a_r[u] * 64 + p * 8) =
                    cvt8u(areg[u][0], areg[u][1]);
            }
        };
        auto stageB = [&](int kc, unsigned short* Bb) {
            #pragma unroll
            for (int t = 0; t < 5; ++t)
                gl_lds16(bsrc[t] + kc, Bb + bdst[t]);
        };
        auto compute = [&](const unsigned short* Ab,
                           const unsigned short* Bb) {
            #pragma unroll
            for (int h = 0; h < 2; ++h) {
                bf16x8 afr[MT], bfr[NTPW];
                #pragma unroll
                for (int m = 0; m < MT; ++m) {
                    const int row = mh * 64 + m * 16 + l15;
                    const int p   = (quad + h * 4 + row) & 7;
                    afr[m] = *reinterpret_cast<const bf16x8*>(
                        Ab + row * 64 + p * 8);
                }
                #pragma unroll
                for (int n = 0; n < NTPW; ++n) {
                    const int row = (nf * NTPW + n) * 16 + l15;
                    const int p   = (quad + h * 4 + row) & 7;
                    bfr[n] = *reinterpret_cast<const bf16x8*>(
                        Bb + row * 64 + p * 8);
                }
                #pragma unroll
                for (int n = 0; n < NTPW; ++n)
                    #pragma unroll
                    for (int m = 0; m < MT; ++m)
                        acc[m][n] = __builtin_amdgcn_mfma_f32_16x16x32_bf16(
                            afr[m], bfr[n], acc[m][n], 0, 0, 0);
            }
        };

        // prologue: stage chunk 0 into buffer 0
        loadA(0);
        stageB(0, Bbuf[0]);
        writeA(Abuf[0]);
        #pragma unroll 1
        for (int c = 0; c < NCHUNK; ++c) {
            const int cur = c & 1;
            __syncthreads();            // drains chunk-c staging; buf^1 free
            if (c + 1 < NCHUNK) {
                loadA((c + 1) * BK);                 // globals fly over compute
                stageB((c + 1) * BK, Bbuf[1 - cur]); // dma flies over compute
            }
            compute(Abuf[cur], Bbuf[cur]);
            if (c + 1 < NCHUNK) writeA(Abuf[1 - cur]);  // cvt after compute
        }
    } else {
        // fallback: both fp32, plain loop (correctness insurance, no ws)
        const float* af = x + (size_t)(row0 + mh * 64 + l15) * D_DIM + quad * 8;
        const float* bf32 = (const float*)b_any
                          + (size_t)((nf * NTPW) * 16 + l15) * D_DIM + quad * 8;
        for (int step = 0; step < 32; ++step) {
            const int off = step * 32;
            bf16x8 afr[MT];
            #pragma unroll
            for (int m = 0; m < MT; ++m) {
                float4 a0 = *reinterpret_cast<const float4*>(af + (size_t)m * 16 * D_DIM + off);
                float4 a1 = *reinterpret_cast<const float4*>(af + (size_t)m * 16 * D_DIM + off + 4);
                afr[m] = cvt8(a0, a1);
            }
            #pragma unroll
            for (int n = 0; n < NTPW; ++n) {
                float4 b0v = *reinterpret_cast<const float4*>(bf32 + (size_t)n * 16 * D_DIM + off);
                float4 b1v = *reinterpret_cast<const float4*>(bf32 + (size_t)n * 16 * D_DIM + off + 4);
                const bf16x8 bfr = cvt8(b0v, b1v);
                #pragma unroll
                for (int m = 0; m < MT; ++m)
                    acc[m][n] = __builtin_amdgcn_mfma_f32_16x16x32_bf16(
                        afr[m], bfr, acc[m][n], 0, 0, 0);
            }
        }
    }

    // ---- epilogue ----
    // C/D layout: col = l15 (within tile), row = quad*4 + reg   [m89/m91]
    const float fcw0 = fcw[l15 & 3];        // fc_w[0][k], k = col&3
    const float fcw1 = fcw[4 + (l15 & 3)];  // fc_w[1][k]

    float p0[MT][4], p1[MT][4];
    #pragma unroll
    for (int m = 0; m < MT; ++m)
        #pragma unroll
        for (int r = 0; r < 4; ++r) { p0[m][r] = 0.f; p1[m][r] = 0.f; }

    #pragma unroll
    for (int n = 0; n < NTPW; ++n) {
        const int col = (nf * NTPW + n) * 16 + l15;     // global n index
        const float bias = b1[col];
        const float tw   = fw[col >> 2];                // final_weight[t]
        #pragma unroll
        for (int m = 0; m < MT; ++m) {
            #pragma unroll
            for (int r = 0; r < 4; ++r) {
                float split = acc[m][n][r] + bias;
                float s = split;                        // sum over k: lanes ^1,^2
                s += __shfl_xor(s, 1);
                s += __shfl_xor(s, 2);
                float leaf = 1.0f / (1.0f + __expf(-split));
                float val  = tw * leaf * s;
                p0[m][r] += val * fcw0;
                p1[m][r] += val * fcw1;
            }
        }
    }

    #pragma unroll
    for (int m = 0; m < MT; ++m) {
        #pragma unroll
        for (int r = 0; r < 4; ++r) {
            float a0s = p0[m][r], a1s = p1[m][r];
            #pragma unroll
            for (int mask = 1; mask < 16; mask <<= 1) {
                a0s += __shfl_xor(a0s, mask);
                a1s += __shfl_xor(a1s, mask);
            }
            const int row = mh * 64 + m * 16 + quad * 4 + r;  // 0..127
            if (l15 == 0) Pbuf[(row * NTPW + nf) * 2 + 0] = a0s;
            if (l15 == 1) Pbuf[(row * NTPW + nf) * 2 + 1] = a1s;
        }
    }
    __syncthreads();

    if (tid < 2 * BM) {
        const int r = tid >> 1, j = tid & 1;
        float s = fcb[j];
        #pragma unroll
        for (int w = 0; w < NTPW; ++w)
            s += Pbuf[(r * NTPW + w) * 2 + j];
        out[(row0 + r) * 2 + j] = s;
    }
}

extern "C" void kernel_launch(void* const* d_in, const int* in_sizes, int n_in,
                              void* d_out, int out_size, void* d_ws, size_t ws_size,
                              hipStream_t stream) {
    const float* x   = (const float*)d_in[0];
    const float* W1  = (const float*)d_in[1];
    const float* b1  = (const float*)d_in[2];
    const float* fw  = (const float*)d_in[3];
    const float* fcw = (const float*)d_in[4];
    const float* fcb = (const float*)d_in[5];
    float* out = (float*)d_out;

    const size_t w1_elems = (size_t)N_COLS * D_DIM;   // 409,600
    if (ws_size >= w1_elems * sizeof(unsigned short)) {
        unsigned short* w1b = (unsigned short*)d_ws;
        cvt_f32_bf16_kernel<<<(int)(w1_elems / 2048), 256, 0, stream>>>(W1, w1b);
        xgb_v6<0><<<B_ROWS / BM, THREADS, 0, stream>>>(
            x, (const void*)w1b, b1, fw, fcw, fcb, out);
    } else {
        xgb_v6<2><<<B_ROWS / BM, THREADS, 0, stream>>>(
            x, (const void*)W1, b1, fw, fcw, fcb, out);
    }
}

// Round 7
// 248.410 us; speedup vs baseline: 1.0596x; 1.0596x over previous
//
#include <hip/hip_runtime.h>
#include <hip/hip_bf16.h>

// DifferentiableXGB: logits = epilogue(x @ W1^T + b1)
//   split[b,n] = sum_d x[b,d]*W1[n,d] + b1[n]          (n = t*4+k, N=400)
//   S[b,t] = sum_k split[b,t,k]
//   logits[b,j] = sum_t fw[t]*S[b,t]*sum_k sigmoid(split[b,t,k])*fc_w[j,k] + fc_b[j]
//
// V7 = V6 with STATIC A-staging indexing.
// R6 post-mortem: WRITE_SIZE ~99 MB + VGPR=84 persisted under (640,1) ->
// the scratch traffic was a forced stack alloc, not a register cap:
// a_r[a_n]/a_c[a_n] runtime-index writes + 'for(u<a_n)' runtime trip made
// areg un-SROA-able, so the A prefetch round-tripped through scratch (HBM)
// every chunk. V7: thread tid owns sub-chunk tid (always) and tid+640 iff
// tid<384 (compile-time unroll, wave-uniform guard: waves 0..5) with named
// regs areg0/areg1 -> everything register-resident.
//   - BM=128 x BN=400, BK=64, 640 threads (2 mh x 5 nf waves), 256 blocks.
//   - LDS double-buffer, ONE barrier per chunk; c+1 staging overlaps
//     compute(c).
//   - XOR-rotate swizzle phys_sub=(sub+row)&7 -> 0 bank conflicts (R5/R6).
//   - A staged fused from fp32 x (read once from HBM, cvt in regs).
//   - B (W1 bf16 in ws) via global_load_lds dwordx4.

typedef __bf16 bf16x8 __attribute__((ext_vector_type(8)));
typedef float f32x4 __attribute__((ext_vector_type(4)));

#define B_ROWS 32768
#define D_DIM  1024
#define N_COLS 400
#define BM     128
#define BK     64
#define NCHUNK 16          // 1024 / 64
#define THREADS 640        // 10 waves: mh = wave/5 (2), nf = wave%5 (5)
#define NTPW 5             // n-tiles (16 wide) per wave
#define MT   4             // m-tiles (16 tall) per wave (64 rows per mh)

__device__ __forceinline__ unsigned short f2bf(float f) {
    unsigned int u = __float_as_uint(f);
    u += 0x7FFFu + ((u >> 16) & 1u);   // RTNE
    return (unsigned short)(u >> 16);
}
__device__ __forceinline__ unsigned int pk2(float a, float b) {
    return (unsigned int)f2bf(a) | ((unsigned int)f2bf(b) << 16);
}
__device__ __forceinline__ uint4 cvt8u(float4 a, float4 b) {
    uint4 u;
    u.x = pk2(a.x, a.y); u.y = pk2(a.z, a.w);
    u.z = pk2(b.x, b.y); u.w = pk2(b.z, b.w);
    return u;
}
__device__ __forceinline__ bf16x8 cvt8(float4 a, float4 b) {
    return __builtin_bit_cast(bf16x8, cvt8u(a, b));
}

// tiny: W1 fp32 -> bf16 (1.6 MB)
__global__ void cvt_f32_bf16_kernel(const float* __restrict__ in,
                                    unsigned short* __restrict__ out) {
    size_t i = ((size_t)blockIdx.x * 256 + threadIdx.x) * 8;
    float4 v0 = *reinterpret_cast<const float4*>(in + i);
    float4 v1 = *reinterpret_cast<const float4*>(in + i + 4);
    *reinterpret_cast<uint4*>(out + i) = cvt8u(v0, v1);
}

// async 16B/lane global->LDS; lds dest = wave-uniform base + lane*16 (HW)
__device__ __forceinline__ void gl_lds16(const unsigned short* g,
                                         unsigned short* l) {
    __builtin_amdgcn_global_load_lds(
        (const __attribute__((address_space(1))) unsigned int*)g,
        (__attribute__((address_space(3))) unsigned int*)l,
        16, 0, 0);
}

// MODE 0: A fp32 (fused cvt), B bf16 (ws). MODE 2: both fp32, plain loop.
template <int MODE>
__global__ __launch_bounds__(THREADS, 1) void xgb_v7(
    const float* __restrict__ x,
    const void*  __restrict__ b_any,
    const float* __restrict__ b1,
    const float* __restrict__ fw,
    const float* __restrict__ fcw,      // [2,4]
    const float* __restrict__ fcb,      // [2]
    float* __restrict__ out)            // [B,2]
{
    // double-buffered tiles; rows of 64 shorts, sub-chunk = 8 shorts (16 B),
    // swizzle: phys_sub = (sub + row) & 7
    __shared__ __align__(16) unsigned short Abuf[2][BM * BK];       // 32 KB
    __shared__ __align__(16) unsigned short Bbuf[2][N_COLS * BK];   // 100 KB
    __shared__ float Pbuf[BM * NTPW * 2];                           // 5 KB

    const int tid  = threadIdx.x;
    const int wave = tid >> 6;
    const int lane = tid & 63;
    const int quad = lane >> 4;
    const int l15  = lane & 15;
    const int mh   = wave / 5;          // 0..1  (m half: 64 rows)
    const int nf   = wave % 5;          // 0..4  (n fifth: 5 tiles)
    const int row0 = blockIdx.x * BM;

    f32x4 acc[MT][NTPW] = {};

    if (MODE == 0) {
        const unsigned short* w1b = (const unsigned short*)b_any;

        // ---- B staging: 50 dma instrs, 5 per wave. stage s covers rows
        // 8s..8s+7. lane i -> row 8s+(i>>3); it fetches the logical sub
        // that belongs at phys slot i&7:  sub = ((i&7) - row) & 7.
        const unsigned short* bsrc[5];
        int bdst[5];
        #pragma unroll
        for (int t = 0; t < 5; ++t) {
            const int s  = wave + 10 * t;          // 0..49
            const int rr = lane >> 3;              // row within stage group
            const int c  = ((lane & 7) - rr) & 7;  // logical sub for slot
            bsrc[t] = w1b + (size_t)(s * 8 + rr) * D_DIM + c * 8;
            bdst[t] = s * 512;                     // shorts
        }

        // ---- A staging: 1024 sub-chunks (128 rows x 8 subs). STATIC map:
        // slot0 = tid (all threads), slot1 = tid+640 (tid<384: waves 0..5,
        // wave-uniform guard, compile-time indices -> register-resident).
        const int r0a = tid >> 3,          c0a = tid & 7;
        const int r1a = (tid + 640) >> 3,  c1a = (tid + 640) & 7;
        const bool hasU1 = (tid < 384);
        const float* asrc0 = x + (size_t)(row0 + r0a) * D_DIM + c0a * 8;
        const float* asrc1 = x + (size_t)(row0 + r1a) * D_DIM + c1a * 8;
        const int adst0 = r0a * 64 + (((c0a + r0a) & 7)) * 8;   // swizzled
        const int adst1 = r1a * 64 + (((c1a + r1a) & 7)) * 8;
        float4 areg0[2], areg1[2];

        auto loadA = [&](int kc) {
            areg0[0] = *reinterpret_cast<const float4*>(asrc0 + kc);
            areg0[1] = *reinterpret_cast<const float4*>(asrc0 + kc + 4);
            if (hasU1) {
                areg1[0] = *reinterpret_cast<const float4*>(asrc1 + kc);
                areg1[1] = *reinterpret_cast<const float4*>(asrc1 + kc + 4);
            }
        };
        auto writeA = [&](unsigned short* Ab) {
            *reinterpret_cast<uint4*>(Ab + adst0) = cvt8u(areg0[0], areg0[1]);
            if (hasU1)
                *reinterpret_cast<uint4*>(Ab + adst1) = cvt8u(areg1[0], areg1[1]);
        };
        auto stageB = [&](int kc, unsigned short* Bb) {
            #pragma unroll
            for (int t = 0; t < 5; ++t)
                gl_lds16(bsrc[t] + kc, Bb + bdst[t]);
        };
        auto compute = [&](const unsigned short* Ab,
                           const unsigned short* Bb) {
            #pragma unroll
            for (int h = 0; h < 2; ++h) {
                bf16x8 afr[MT], bfr[NTPW];
                #pragma unroll
                for (int m = 0; m < MT; ++m) {
                    const int row = mh * 64 + m * 16 + l15;
                    const int p   = (quad + h * 4 + row) & 7;
                    afr[m] = *reinterpret_cast<const bf16x8*>(
                        Ab + row * 64 + p * 8);
                }
                #pragma unroll
                for (int n = 0; n < NTPW; ++n) {
                    const int row = (nf * NTPW + n) * 16 + l15;
                    const int p   = (quad + h * 4 + row) & 7;
                    bfr[n] = *reinterpret_cast<const bf16x8*>(
                        Bb + row * 64 + p * 8);
                }
                #pragma unroll
                for (int n = 0; n < NTPW; ++n)
                    #pragma unroll
                    for (int m = 0; m < MT; ++m)
                        acc[m][n] = __builtin_amdgcn_mfma_f32_16x16x32_bf16(
                            afr[m], bfr[n], acc[m][n], 0, 0, 0);
            }
        };

        // prologue: stage chunk 0 into buffer 0
        loadA(0);
        stageB(0, Bbuf[0]);
        writeA(Abuf[0]);
        #pragma unroll 1
        for (int c = 0; c < NCHUNK; ++c) {
            const int cur = c & 1;
            __syncthreads();            // drains chunk-c staging; buf^1 free
            if (c + 1 < NCHUNK) {
                loadA((c + 1) * BK);                 // globals fly over compute
                stageB((c + 1) * BK, Bbuf[1 - cur]); // dma flies over compute
            }
            compute(Abuf[cur], Bbuf[cur]);
            if (c + 1 < NCHUNK) writeA(Abuf[1 - cur]);  // cvt after compute
        }
    } else {
        // fallback: both fp32, plain loop (correctness insurance, no ws)
        const float* af = x + (size_t)(row0 + mh * 64 + l15) * D_DIM + quad * 8;
        const float* bf32 = (const float*)b_any
                          + (size_t)((nf * NTPW) * 16 + l15) * D_DIM + quad * 8;
        for (int step = 0; step < 32; ++step) {
            const int off = step * 32;
            bf16x8 afr[MT];
            #pragma unroll
            for (int m = 0; m < MT; ++m) {
                float4 a0 = *reinterpret_cast<const float4*>(af + (size_t)m * 16 * D_DIM + off);
                float4 a1 = *reinterpret_cast<const float4*>(af + (size_t)m * 16 * D_DIM + off + 4);
                afr[m] = cvt8(a0, a1);
            }
            #pragma unroll
            for (int n = 0; n < NTPW; ++n) {
                float4 b0v = *reinterpret_cast<const float4*>(bf32 + (size_t)n * 16 * D_DIM + off);
                float4 b1v = *reinterpret_cast<const float4*>(bf32 + (size_t)n * 16 * D_DIM + off + 4);
                const bf16x8 bfr = cvt8(b0v, b1v);
                #pragma unroll
                for (int m = 0; m < MT; ++m)
                    acc[m][n] = __builtin_amdgcn_mfma_f32_16x16x32_bf16(
                        afr[m], bfr, acc[m][n], 0, 0, 0);
            }
        }
    }

    // ---- epilogue ----
    // C/D layout: col = l15 (within tile), row = quad*4 + reg   [m89/m91]
    const float fcw0 = fcw[l15 & 3];        // fc_w[0][k], k = col&3
    const float fcw1 = fcw[4 + (l15 & 3)];  // fc_w[1][k]

    float p0[MT][4], p1[MT][4];
    #pragma unroll
    for (int m = 0; m < MT; ++m)
        #pragma unroll
        for (int r = 0; r < 4; ++r) { p0[m][r] = 0.f; p1[m][r] = 0.f; }

    #pragma unroll
    for (int n = 0; n < NTPW; ++n) {
        const int col = (nf * NTPW + n) * 16 + l15;     // global n index
        const float bias = b1[col];
        const float tw   = fw[col >> 2];                // final_weight[t]
        #pragma unroll
        for (int m = 0; m < MT; ++m) {
            #pragma unroll
            for (int r = 0; r < 4; ++r) {
                float split = acc[m][n][r] + bias;
                float s = split;                        // sum over k: lanes ^1,^2
                s += __shfl_xor(s, 1);
                s += __shfl_xor(s, 2);
                float leaf = 1.0f / (1.0f + __expf(-split));
                float val  = tw * leaf * s;
                p0[m][r] += val * fcw0;
                p1[m][r] += val * fcw1;
            }
        }
    }

    #pragma unroll
    for (int m = 0; m < MT; ++m) {
        #pragma unroll
        for (int r = 0; r < 4; ++r) {
            float a0s = p0[m][r], a1s = p1[m][r];
            #pragma unroll
            for (int mask = 1; mask < 16; mask <<= 1) {
                a0s += __shfl_xor(a0s, mask);
                a1s += __shfl_xor(a1s, mask);
            }
            const int row = mh * 64 + m * 16 + quad * 4 + r;  // 0..127
            if (l15 == 0) Pbuf[(row * NTPW + nf) * 2 + 0] = a0s;
            if (l15 == 1) Pbuf[(row * NTPW + nf) * 2 + 1] = a1s;
        }
    }
    __syncthreads();

    if (tid < 2 * BM) {
        const int r = tid >> 1, j = tid & 1;
        float s = fcb[j];
        #pragma unroll
        for (int w = 0; w < NTPW; ++w)
            s += Pbuf[(r * NTPW + w) * 2 + j];
        out[(row0 + r) * 2 + j] = s;
    }
}

extern "C" void kernel_launch(void* const* d_in, const int* in_sizes, int n_in,
                              void* d_out, int out_size, void* d_ws, size_t ws_size,
                              hipStream_t stream) {
    const float* x   = (const float*)d_in[0];
    const float* W1  = (const float*)d_in[1];
    const float* b1  = (const float*)d_in[2];
    const float* fw  = (const float*)d_in[3];
    const float* fcw = (const float*)d_in[4];
    const float* fcb = (const float*)d_in[5];
    float* out = (float*)d_out;

    const size_t w1_elems = (size_t)N_COLS * D_DIM;   // 409,600
    if (ws_size >= w1_elems * sizeof(unsigned short)) {
        unsigned short* w1b = (unsigned short*)d_ws;
        cvt_f32_bf16_kernel<<<(int)(w1_elems / 2048), 256, 0, stream>>>(W1, w1b);
        xgb_v7<0><<<B_ROWS / BM, THREADS, 0, stream>>>(
            x, (const void*)w1b, b1, fw, fcw, fcb, out);
    } else {
        xgb_v7<2><<<B_ROWS / BM, THREADS, 0, stream>>>(
            x, (const void*)W1, b1, fw, fcw, fcb, out);
    }
}